// Round 5
// baseline (423.925 us; speedup 1.0000x reference)
//
#include <hip/hip_runtime.h>
#include <stdint.h>

#define GSZ 60
#define KNB 13
#define NPT 512

typedef __attribute__((ext_vector_type(4))) float f32x4;
typedef __attribute__((ext_vector_type(8))) short s16x8;

__device__ __forceinline__ ushort f2bf(float f) {
  union { float f; unsigned u; } v; v.f = f;
  unsigned r = v.u + 0x7fffu + ((v.u >> 16) & 1u);
  return (ushort)(r >> 16);
}
__device__ __forceinline__ float bf2f(ushort h) {
  union { unsigned u; float f; } v; v.u = ((unsigned)h) << 16;
  return v.f;
}

// async global->LDS, 16B per lane; dst must be wave-uniform (HW adds lane*16)
__device__ __forceinline__ void gload_lds16(const void* gsrc, void* ldst) {
  __builtin_amdgcn_global_load_lds(
      (const __attribute__((address_space(1))) uint32_t*)gsrc,
      (__attribute__((address_space(3))) uint32_t*)ldst, 16, 0, 0);
}

// feats [N][32][G] fp32 -> X0 [61][N][32] bf16 (panel 60 = zeros, L1 K-padding)
__global__ __launch_bounds__(256) void prep_feats_k(const float* __restrict__ feats,
                                                    ushort* __restrict__ X0) {
  int idx = blockIdx.x * 256 + threadIdx.x;
  if (idx >= 61 * NPT * 32) return;
  int c = idx & 31;
  int t = idx >> 5;
  int n = t % NPT;
  int g = t / NPT;
  X0[idx] = (g < GSZ) ? f2bf(feats[(n * 32 + c) * GSZ + g]) : (ushort)0;
}

// W [O][C][13] fp32 -> Wb [OPAD][KPAD] bf16, Wb[o][k*C+c] = W[o][c][k], zero-padded
__global__ __launch_bounds__(256) void prep_wb_k(const float* __restrict__ W,
                                                 ushort* __restrict__ Wb,
                                                 int O, int OPAD, int C, int KPAD) {
  int idx = blockIdx.x * 256 + threadIdx.x;
  if (idx >= OPAD * KPAD) return;
  int o = idx / KPAD;
  int kk = idx - o * KPAD;
  int k = kk / C;
  int c = kk - k * C;
  Wb[idx] = (o < O && k < KNB) ? f2bf(W[(o * C + c) * KNB + k]) : (ushort)0;
}

// ---------------- 4-wave 128xBN dbuf kernel (L1, L4 split-K) ----------------
template <int CIN, int KTOT, int OPAD, int OREAL, int BN, int MODE, bool RELU>
__global__ __launch_bounds__(256) void comb_gemm(
    const ushort* __restrict__ Xin, const ushort* __restrict__ Wb,
    const float* __restrict__ bias, const int* __restrict__ nei,
    ushort* __restrict__ Xout, float* __restrict__ Eq,
    const float* __restrict__ feats, int qb, int qe) {
  constexpr int BM = 128;
  constexpr int BK = 64;
  constexpr int TO = OPAD / BN;
  constexpr int TN = NPT / BM;
  constexpr int WN = BN / 2;
  constexpr int N_REP = WN / 16;
  constexpr int M_REP = 4;
  constexpr int CSH = (CIN == 32) ? 5 : (CIN == 256) ? 8 : 9;
  static_assert(CIN == (1 << CSH), "CIN pow2");

  __shared__ ushort smA[2][BM * BK];
  __shared__ ushort smB[2][BN * BK];
  __shared__ int nei_sh[16];

  const int nwg = TO * TN * GSZ;
  const int cpx = nwg >> 3;
  const int bid = blockIdx.x;
  const int idx = (bid & 7) * cpx + (bid >> 3);
  const int g = idx / (TO * TN);
  const int rem = idx - g * (TO * TN);
  const int nt = rem / TO;
  const int ot = rem - nt * TO;
  const int n0 = nt * BM;
  const int o0 = ot * BN;

  const int t = threadIdx.x;
  if (t < 14) nei_sh[t] = (t < KNB) ? nei[g * KNB + t] : GSZ;
  __syncthreads();

  const int w = t >> 6;
  const int l = t & 63;
  const int lrow = l & 15;
  const int lkg = l >> 4;
  const int wr = w >> 1;
  const int wc = w & 1;
  const int srow_w = w * 8;
  const int sr = l >> 3;
  const int slot = l & 7;

  int laneA[BM / 32], laneB[BN / 32], swz[BM / 32];
#pragma unroll
  for (int j = 0; j < BM / 32; ++j) {
    const int r = j * 32 + srow_w + sr;
    swz[j] = (slot ^ (r & 7)) << 3;
    laneA[j] = ((n0 + r) << CSH) + swz[j];
  }
#pragma unroll
  for (int j = 0; j < BN / 32; ++j) {
    const int r = j * 32 + srow_w + sr;
    laneB[j] = (o0 + r) * KTOT + ((slot ^ (r & 7)) << 3);
  }

  auto stage = [&](int buf, int q) {
    const int c0 = q * BK;
    if constexpr (CIN >= 64) {
      const int pbase = nei_sh[c0 >> CSH] * (NPT << CSH) + (c0 & (CIN - 1));
#pragma unroll
      for (int j = 0; j < BM / 32; ++j)
        gload_lds16(Xin + pbase + laneA[j], &smA[buf][(j * 32 + srow_w) * BK]);
    } else {
#pragma unroll
      for (int j = 0; j < BM / 32; ++j) {
        const int r = j * 32 + srow_w + sr;
        const int kk = c0 + swz[j];
        const int nbr = kk >> CSH;
        const int cc = kk & (CIN - 1);
        gload_lds16(Xin + ((nei_sh[nbr] * NPT + n0 + r) << CSH) + cc,
                    &smA[buf][(j * 32 + srow_w) * BK]);
      }
    }
#pragma unroll
    for (int j = 0; j < BN / 32; ++j)
      gload_lds16(Wb + laneB[j] + c0, &smB[buf][(j * 32 + srow_w) * BK]);
  };

  f32x4 acc[M_REP][N_REP] = {};

  stage(0, qb);
  asm volatile("s_waitcnt vmcnt(0)" ::: "memory");
  __builtin_amdgcn_s_barrier();

  int cur = 0;
#pragma unroll 1
  for (int q = qb; q < qe; ++q) {
    if (q + 1 < qe) stage(cur ^ 1, q + 1);
#pragma unroll
    for (int ks = 0; ks < 2; ++ks) {
      const int cb = ks * 4 + lkg;
      s16x8 bf[N_REP];
#pragma unroll
      for (int n = 0; n < N_REP; ++n) {
        const int r = wc * WN + n * 16 + lrow;
        bf[n] = *(const s16x8*)&smB[cur][r * BK + ((cb ^ (r & 7)) << 3)];
      }
#pragma unroll
      for (int m = 0; m < M_REP; ++m) {
        const int r = wr * 64 + m * 16 + lrow;
        s16x8 af = *(const s16x8*)&smA[cur][r * BK + ((cb ^ (r & 7)) << 3)];
#pragma unroll
        for (int n = 0; n < N_REP; ++n)
          acc[m][n] = __builtin_amdgcn_mfma_f32_16x16x32_bf16(af, bf[n], acc[m][n], 0, 0, 0);
      }
    }
    asm volatile("s_waitcnt vmcnt(0)" ::: "memory");
    __builtin_amdgcn_s_barrier();
    cur ^= 1;
  }

#pragma unroll
  for (int m = 0; m < M_REP; ++m) {
#pragma unroll
    for (int n = 0; n < N_REP; ++n) {
      const int oc = o0 + wc * WN + n * 16 + lrow;
      float bv;
      if (MODE == 2)
        bv = (oc < OREAL && feats) ? bias[oc] : 0.f;
      else
        bv = bias[oc];
#pragma unroll
      for (int r = 0; r < 4; ++r) {
        const int row = n0 + wr * 64 + m * 16 + lkg * 4 + r;
        float v = acc[m][n][r] + bv;
        if (MODE == 0) {
          if (RELU) v = v > 0.f ? v : 0.f;
          Xout[((size_t)g * NPT + row) * OPAD + oc] = f2bf(v);
        } else if (MODE == 1) {
          const size_t ix = ((size_t)g * NPT + row) * OPAD + oc;
          Xout[ix] = f2bf(bf2f(Xout[ix]) + v);
        } else {
          const float add = (oc < OREAL && feats) ? feats[((size_t)row * 32 + oc) * GSZ + g] : 0.f;
          Eq[((size_t)g * NPT + row) * 64 + oc] = v + add;
        }
      }
    }
  }
}

// ------- 8-wave 128x256 deep-pipelined kernel (L2, L3): 3 LDS bufs, counted vmcnt -------
// Per iter: stage(q+2) -> compute(q) -> vmcnt(6) -> barrier. Loads span 2 chunks.
template <int CIN, int KTOT, int OPAD, int MODE, bool RELU>
__global__ __launch_bounds__(512) void comb_gemm_d(
    const ushort* __restrict__ Xin, const ushort* __restrict__ Wb,
    const float* __restrict__ bias, const int* __restrict__ nei,
    ushort* __restrict__ Xout) {
  constexpr int BM = 128, BN = 256, BK = 64;
  constexpr int NCH = KTOT / BK;
  constexpr int TO = OPAD / BN;
  constexpr int TN = NPT / BM;  // 4
  constexpr int WM = 64, WN = 64;  // 8 waves as 2M x 4N
  constexpr int M_REP = 4, N_REP = 4;
  constexpr int CSH = (CIN == 256) ? 8 : 9;
  static_assert(CIN == (1 << CSH), "CIN pow2");

  __shared__ ushort smA[3][BM * BK];  // 48 KB
  __shared__ ushort smB[3][BN * BK];  // 96 KB
  __shared__ int nei_sh[16];

  const int nwg = TO * TN * GSZ;
  const int cpx = nwg >> 3;
  const int bid = blockIdx.x;
  const int idx = (bid & 7) * cpx + (bid >> 3);
  const int g = idx / (TO * TN);
  const int rem = idx - g * (TO * TN);
  const int nt = rem / TO;
  const int ot = rem - nt * TO;
  const int n0 = nt * BM;
  const int o0 = ot * BN;

  const int t = threadIdx.x;
  if (t < 14) nei_sh[t] = (t < KNB) ? nei[g * KNB + t] : GSZ;
  __syncthreads();

  const int w = t >> 6;   // 0..7
  const int l = t & 63;
  const int lrow = l & 15;
  const int lkg = l >> 4;
  const int wr = w >> 2;  // 0..1
  const int wc = w & 3;   // 0..3
  const int sr = l >> 3;
  const int slot = l & 7;
  const int swz = (slot ^ sr) << 3;  // rows staged at 8-row-aligned bases: (r&7)==sr
  const int srow_w = w * 8;

  // chunk-invariant per-lane staging offsets (elements)
  int laneA[2], laneB[4];
#pragma unroll
  for (int j = 0; j < 2; ++j)
    laneA[j] = ((n0 + j * 64 + srow_w + sr) << CSH) + swz;
#pragma unroll
  for (int j = 0; j < 4; ++j)
    laneB[j] = (o0 + j * 64 + srow_w + sr) * KTOT + swz;

  auto stage = [&](int buf, int q) {
    const int c0 = q * BK;
    const int pbase = nei_sh[c0 >> CSH] * (NPT << CSH) + (c0 & (CIN - 1));
#pragma unroll
    for (int j = 0; j < 2; ++j)
      gload_lds16(Xin + pbase + laneA[j], &smA[buf][(j * 64 + srow_w) * BK]);
#pragma unroll
    for (int j = 0; j < 4; ++j)
      gload_lds16(Wb + laneB[j] + c0, &smB[buf][(j * 64 + srow_w) * BK]);
  };

  f32x4 acc[M_REP][N_REP] = {};

  // prologue: 2 chunks in flight
  stage(0, 0);
  stage(1, 1);
  asm volatile("s_waitcnt vmcnt(6)" ::: "memory");  // buf0 ready, buf1 in flight
  __builtin_amdgcn_s_barrier();

  int bc = 0;  // compute buffer = q % 3
#pragma unroll 1
  for (int q = 0; q < NCH; ++q) {
    if (q + 2 < NCH) stage(bc ? bc - 1 : 2, q + 2);  // (q+2)%3 == (q-1)%3
#pragma unroll
    for (int ks = 0; ks < 2; ++ks) {
      const int cb = ks * 4 + lkg;
      s16x8 bf[N_REP];
#pragma unroll
      for (int n = 0; n < N_REP; ++n) {
        const int r = wc * WN + n * 16 + lrow;
        bf[n] = *(const s16x8*)&smB[bc][r * BK + ((cb ^ (r & 7)) << 3)];
      }
#pragma unroll
      for (int m = 0; m < M_REP; ++m) {
        const int r = wr * WM + m * 16 + lrow;
        s16x8 af = *(const s16x8*)&smA[bc][r * BK + ((cb ^ (r & 7)) << 3)];
#pragma unroll
        for (int n = 0; n < N_REP; ++n)
          acc[m][n] = __builtin_amdgcn_mfma_f32_16x16x32_bf16(af, bf[n], acc[m][n], 0, 0, 0);
      }
    }
    // next buffer ready; keep newest 6 loads (chunk q+2) in flight
    if (q + 2 < NCH)
      asm volatile("s_waitcnt vmcnt(6)" ::: "memory");
    else
      asm volatile("s_waitcnt vmcnt(0)" ::: "memory");
    __builtin_amdgcn_s_barrier();
    bc = (bc == 2) ? 0 : bc + 1;
  }

#pragma unroll
  for (int m = 0; m < M_REP; ++m) {
#pragma unroll
    for (int n = 0; n < N_REP; ++n) {
      const int oc = o0 + wc * WN + n * 16 + lrow;
      const float bv = bias[oc];
#pragma unroll
      for (int r = 0; r < 4; ++r) {
        const int row = n0 + wr * WM + m * 16 + lkg * 4 + r;
        float v = acc[m][n][r] + bv;
        if (MODE == 0) {
          if (RELU) v = v > 0.f ? v : 0.f;
          Xout[((size_t)g * NPT + row) * OPAD + oc] = f2bf(v);
        } else {  // MODE 1: residual accumulate
          const size_t ix = ((size_t)g * NPT + row) * OPAD + oc;
          Xout[ix] = f2bf(bf2f(Xout[ix]) + v);
        }
      }
    }
  }
}

// Eq4: 4 split-K partials [4][G][N][64] fp32 -> out: inv [N][32], eqv [N][32][G]
__global__ __launch_bounds__(256) void finalize_k(const float* __restrict__ Eq,
                                                  float* __restrict__ out) {
  const int n = blockIdx.x;
  const int t = threadIdx.x;
  const int c = t & 31;
  const int gs = t >> 5;
  constexpr size_t PART = (size_t)GSZ * NPT * 64;

  float invp = 0.f;
  for (int g = gs; g < GSZ; g += 8) {
    const size_t base = ((size_t)g * NPT + n) * 64 + c;
    float x = Eq[base] + Eq[PART + base] + Eq[2 * PART + base] + Eq[3 * PART + base];
    invp += x;
    float ss = x * x;
#pragma unroll
    for (int m = 16; m >= 1; m >>= 1) ss += __shfl_xor(ss, m, 64);
    float nrm = sqrtf(ss);
    nrm = nrm > 1e-4f ? nrm : 1e-4f;
    out[16384 + ((size_t)n * 32 + c) * GSZ + g] = x / nrm;
  }

  __shared__ float tmp[8][32];
  tmp[gs][c] = invp;
  __syncthreads();
  if (t < 32) {
    float s = 0.f;
#pragma unroll
    for (int i = 0; i < 8; ++i) s += tmp[i][t];
    s *= (1.f / 60.f);
    float ss = s * s;
#pragma unroll
    for (int m = 16; m >= 1; m >>= 1) ss += __shfl_xor(ss, m, 64);
    float nrm = sqrtf(ss);
    nrm = nrm > 1e-4f ? nrm : 1e-4f;
    out[(size_t)n * 32 + t] = s / nrm;
  }
}

extern "C" void kernel_launch(void* const* d_in, const int* in_sizes, int n_in,
                              void* d_out, int out_size, void* d_ws, size_t ws_size,
                              hipStream_t stream) {
  const float* feats = (const float*)d_in[0];
  const int* nei = (const int*)d_in[1];
  const float* W_in = (const float*)d_in[2];
  const float* b_in = (const float*)d_in[3];
  const float* W_r1 = (const float*)d_in[4];
  const float* b_r1 = (const float*)d_in[5];
  const float* W_r2 = (const float*)d_in[6];
  const float* b_r2 = (const float*)d_in[7];
  const float* W_out = (const float*)d_in[8];
  const float* b_out = (const float*)d_in[9];
  float* out = (float*)d_out;

  char* ws = (char*)d_ws;
  size_t off = 0;
  auto alloc = [&](size_t bytes) {
    void* p = ws + off;
    off += (bytes + 255) & ~(size_t)255;
    return p;
  };
  ushort* X0 = (ushort*)alloc((size_t)61 * NPT * 32 * 2);    // 2.0 MB
  ushort* H1 = (ushort*)alloc((size_t)GSZ * NPT * 256 * 2);  // 15.7 MB (h1, then h2)
  ushort* R = (ushort*)alloc((size_t)GSZ * NPT * 512 * 2);   // 31.5 MB; later aliased as Eq4
  ushort* Wb_in = (ushort*)alloc((size_t)256 * 448 * 2);
  ushort* Wb_r1 = (ushort*)alloc((size_t)512 * 3328 * 2);
  ushort* Wb_r2 = (ushort*)alloc((size_t)256 * 6656 * 2);
  ushort* Wb_out = (ushort*)alloc((size_t)64 * 3328 * 2);
  float* Eq4 = (float*)R;  // L4 split-K partials [4][G][N][64] fp32 (R dead after L3)

  prep_feats_k<<<(61 * NPT * 32 + 255) / 256, 256, 0, stream>>>(feats, X0);
  prep_wb_k<<<(256 * 448 + 255) / 256, 256, 0, stream>>>(W_in, Wb_in, 256, 256, 32, 448);
  prep_wb_k<<<(512 * 3328 + 255) / 256, 256, 0, stream>>>(W_r1, Wb_r1, 512, 512, 256, 3328);
  prep_wb_k<<<(256 * 6656 + 255) / 256, 256, 0, stream>>>(W_r2, Wb_r2, 256, 256, 512, 6656);
  prep_wb_k<<<(64 * 3328 + 255) / 256, 256, 0, stream>>>(W_out, Wb_out, 32, 64, 256, 3328);

  // L1: 32 -> 256 (KTOT 448, 7 chunks), 4-wave, grid 480
  comb_gemm<32, 448, 256, 256, 128, 0, false><<<dim3(2 * 4 * GSZ), dim3(256), 0, stream>>>(
      X0, Wb_in, b_in, nei, H1, nullptr, nullptr, 0, 7);
  // L2: 256 -> 512, relu; deep 8-wave 128x256, grid 480
  comb_gemm_d<256, 3328, 512, 0, true><<<dim3(2 * 4 * GSZ), dim3(512), 0, stream>>>(
      H1, Wb_r1, b_r1, nei, R);
  // L3: 512 -> 256, h2 = h1 + comb(r); deep 8-wave 128x256, grid 240 (TO=1: A read once)
  comb_gemm_d<512, 6656, 256, 1, false><<<dim3(1 * 4 * GSZ), dim3(512), 0, stream>>>(
      R, Wb_r2, b_r2, nei, H1);
  // L4: 256 -> 32 (pad 64), split-K x4 -> Eq4 partials (R buffer)
  for (int kp = 0; kp < 4; ++kp) {
    comb_gemm<256, 3328, 64, 32, 64, 2, false><<<dim3(1 * 4 * GSZ), dim3(256), 0, stream>>>(
        H1, Wb_out, b_out, nei, nullptr, Eq4 + (size_t)kp * GSZ * NPT * 64,
        kp == 0 ? feats : nullptr, kp * 13, (kp + 1) * 13);
  }
  finalize_k<<<NPT, 256, 0, stream>>>(Eq4, out);
}

// Round 6
// 388.442 us; speedup vs baseline: 1.0913x; 1.0913x over previous
//
#include <hip/hip_runtime.h>
#include <stdint.h>

#define GSZ 60
#define KNB 13
#define NPT 512

typedef __attribute__((ext_vector_type(4))) float f32x4;
typedef __attribute__((ext_vector_type(8))) short s16x8;

__device__ __forceinline__ ushort f2bf(float f) {
  union { float f; unsigned u; } v; v.f = f;
  unsigned r = v.u + 0x7fffu + ((v.u >> 16) & 1u);
  return (ushort)(r >> 16);
}
__device__ __forceinline__ float bf2f(ushort h) {
  union { unsigned u; float f; } v; v.u = ((unsigned)h) << 16;
  return v.f;
}

// async global->LDS, 16B per lane; dst must be wave-uniform (HW adds lane*16)
__device__ __forceinline__ void gload_lds16(const void* gsrc, void* ldst) {
  __builtin_amdgcn_global_load_lds(
      (const __attribute__((address_space(1))) uint32_t*)gsrc,
      (__attribute__((address_space(3))) uint32_t*)ldst, 16, 0, 0);
}

template <int N>
__device__ __forceinline__ void vwaitN() {
  if constexpr (N == 0) asm volatile("s_waitcnt vmcnt(0)" ::: "memory");
  else if constexpr (N == 3) asm volatile("s_waitcnt vmcnt(3)" ::: "memory");
  else if constexpr (N == 4) asm volatile("s_waitcnt vmcnt(4)" ::: "memory");
  else if constexpr (N == 6) asm volatile("s_waitcnt vmcnt(6)" ::: "memory");
  else asm volatile("s_waitcnt vmcnt(8)" ::: "memory");
}

// feats [N][32][G] fp32 -> X0 [61][N][32] bf16 (panel 60 = zeros, L1 K-padding)
__global__ __launch_bounds__(256) void prep_feats_k(const float* __restrict__ feats,
                                                    ushort* __restrict__ X0) {
  int idx = blockIdx.x * 256 + threadIdx.x;
  if (idx >= 61 * NPT * 32) return;
  int c = idx & 31;
  int t = idx >> 5;
  int n = t % NPT;
  int g = t / NPT;
  X0[idx] = (g < GSZ) ? f2bf(feats[(n * 32 + c) * GSZ + g]) : (ushort)0;
}

// W [O][C][13] fp32 -> Wb [OPAD][KPAD] bf16, Wb[o][k*C+c] = W[o][c][k], zero-padded
__global__ __launch_bounds__(256) void prep_wb_k(const float* __restrict__ W,
                                                 ushort* __restrict__ Wb,
                                                 int O, int OPAD, int C, int KPAD) {
  int idx = blockIdx.x * 256 + threadIdx.x;
  if (idx >= OPAD * KPAD) return;
  int o = idx / KPAD;
  int kk = idx - o * KPAD;
  int k = kk / C;
  int c = kk - k * C;
  Wb[idx] = (o < O && k < KNB) ? f2bf(W[(o * C + c) * KNB + k]) : (ushort)0;
}

// ---------------- 4-wave 128xBN dbuf kernel (L1, L4 split-K) — proven ----------------
template <int CIN, int KTOT, int OPAD, int OREAL, int BN, int MODE, bool RELU>
__global__ __launch_bounds__(256) void comb_gemm(
    const ushort* __restrict__ Xin, const ushort* __restrict__ Wb,
    const float* __restrict__ bias, const int* __restrict__ nei,
    ushort* __restrict__ Xout, float* __restrict__ Eq,
    const float* __restrict__ feats, int qb, int qe) {
  constexpr int BM = 128;
  constexpr int BK = 64;
  constexpr int TO = OPAD / BN;
  constexpr int TN = NPT / BM;
  constexpr int WN = BN / 2;
  constexpr int N_REP = WN / 16;
  constexpr int M_REP = 4;
  constexpr int CSH = (CIN == 32) ? 5 : (CIN == 256) ? 8 : 9;
  static_assert(CIN == (1 << CSH), "CIN pow2");

  __shared__ ushort smA[2][BM * BK];
  __shared__ ushort smB[2][BN * BK];
  __shared__ int nei_sh[16];

  const int nwg = TO * TN * GSZ;
  const int cpx = nwg >> 3;
  const int bid = blockIdx.x;
  const int idx = (bid & 7) * cpx + (bid >> 3);
  const int g = idx / (TO * TN);
  const int rem = idx - g * (TO * TN);
  const int nt = rem / TO;
  const int ot = rem - nt * TO;
  const int n0 = nt * BM;
  const int o0 = ot * BN;

  const int t = threadIdx.x;
  if (t < 14) nei_sh[t] = (t < KNB) ? nei[g * KNB + t] : GSZ;
  __syncthreads();

  const int w = t >> 6;
  const int l = t & 63;
  const int lrow = l & 15;
  const int lkg = l >> 4;
  const int wr = w >> 1;
  const int wc = w & 1;
  const int srow_w = w * 8;
  const int sr = l >> 3;
  const int slot = l & 7;

  int laneA[BM / 32], laneB[BN / 32], swz[BM / 32];
#pragma unroll
  for (int j = 0; j < BM / 32; ++j) {
    const int r = j * 32 + srow_w + sr;
    swz[j] = (slot ^ (r & 7)) << 3;
    laneA[j] = ((n0 + r) << CSH) + swz[j];
  }
#pragma unroll
  for (int j = 0; j < BN / 32; ++j) {
    const int r = j * 32 + srow_w + sr;
    laneB[j] = (o0 + r) * KTOT + ((slot ^ (r & 7)) << 3);
  }

  auto stage = [&](int buf, int q) {
    const int c0 = q * BK;
    if constexpr (CIN >= 64) {
      const int pbase = nei_sh[c0 >> CSH] * (NPT << CSH) + (c0 & (CIN - 1));
#pragma unroll
      for (int j = 0; j < BM / 32; ++j)
        gload_lds16(Xin + pbase + laneA[j], &smA[buf][(j * 32 + srow_w) * BK]);
    } else {
#pragma unroll
      for (int j = 0; j < BM / 32; ++j) {
        const int r = j * 32 + srow_w + sr;
        const int kk = c0 + swz[j];
        const int nbr = kk >> CSH;
        const int cc = kk & (CIN - 1);
        gload_lds16(Xin + ((nei_sh[nbr] * NPT + n0 + r) << CSH) + cc,
                    &smA[buf][(j * 32 + srow_w) * BK]);
      }
    }
#pragma unroll
    for (int j = 0; j < BN / 32; ++j)
      gload_lds16(Wb + laneB[j] + c0, &smB[buf][(j * 32 + srow_w) * BK]);
  };

  f32x4 acc[M_REP][N_REP] = {};

  stage(0, qb);
  asm volatile("s_waitcnt vmcnt(0)" ::: "memory");
  __builtin_amdgcn_s_barrier();

  int cur = 0;
#pragma unroll 1
  for (int q = qb; q < qe; ++q) {
    if (q + 1 < qe) stage(cur ^ 1, q + 1);
#pragma unroll
    for (int ks = 0; ks < 2; ++ks) {
      const int cb = ks * 4 + lkg;
      s16x8 bf[N_REP];
#pragma unroll
      for (int n = 0; n < N_REP; ++n) {
        const int r = wc * WN + n * 16 + lrow;
        bf[n] = *(const s16x8*)&smB[cur][r * BK + ((cb ^ (r & 7)) << 3)];
      }
#pragma unroll
      for (int m = 0; m < M_REP; ++m) {
        const int r = wr * 64 + m * 16 + lrow;
        s16x8 af = *(const s16x8*)&smA[cur][r * BK + ((cb ^ (r & 7)) << 3)];
#pragma unroll
        for (int n = 0; n < N_REP; ++n)
          acc[m][n] = __builtin_amdgcn_mfma_f32_16x16x32_bf16(af, bf[n], acc[m][n], 0, 0, 0);
      }
    }
    asm volatile("s_waitcnt vmcnt(0)" ::: "memory");
    __builtin_amdgcn_s_barrier();
    cur ^= 1;
  }

#pragma unroll
  for (int m = 0; m < M_REP; ++m) {
#pragma unroll
    for (int n = 0; n < N_REP; ++n) {
      const int oc = o0 + wc * WN + n * 16 + lrow;
      float bv;
      if (MODE == 2)
        bv = (oc < OREAL && feats) ? bias[oc] : 0.f;
      else
        bv = bias[oc];
#pragma unroll
      for (int r = 0; r < 4; ++r) {
        const int row = n0 + wr * 64 + m * 16 + lkg * 4 + r;
        float v = acc[m][n][r] + bv;
        if (MODE == 0) {
          if (RELU) v = v > 0.f ? v : 0.f;
          Xout[((size_t)g * NPT + row) * OPAD + oc] = f2bf(v);
        } else if (MODE == 1) {
          const size_t ix = ((size_t)g * NPT + row) * OPAD + oc;
          Xout[ix] = f2bf(bf2f(Xout[ix]) + v);
        } else {
          const float add = (oc < OREAL && feats) ? feats[((size_t)row * 32 + oc) * GSZ + g] : 0.f;
          Eq[((size_t)g * NPT + row) * 64 + oc] = v + add;
        }
      }
    }
  }
}

// ---------- 8-phase-style deep kernel (m201 port): BMx256 tile, BK=64 as 2 k-halves ----------
// 512 thr / 8 waves (2M x 4N). LDS: [2 dbuf][2 khalf][rows][32] per matrix, contiguous
// halves so global_load_lds stays linear. 4 phases per K-tile, each:
// {ds_read 4-8 b128 | stage 1 half | barrier | setprio1 | MH*4 MFMA | setprio0 | [vmcnt] | barrier}.
// Swizzle: 16B slot s stored at s ^ ((row>>1)&3) (both source-preswizzle and ds_read).
template <int CIN, int KTOT, int OPAD, int BM, int MODE, bool RELU>
__global__ __launch_bounds__(512) void comb8p(
    const ushort* __restrict__ Xin, const ushort* __restrict__ Wb,
    const float* __restrict__ bias, const int* __restrict__ nei,
    ushort* __restrict__ Xout) {
  constexpr int NT = KTOT / 64;
  constexpr int TN = NPT / BM;
  constexpr int TO = OPAD / 256;
  constexpr int WM = BM / 2;       // per-wave M rows
  constexpr int M_REP = WM / 16;   // 8 (BM=256) or 4 (BM=128)
  constexpr int MH = M_REP / 2;    // MFMA rows per phase
  constexpr int LA = BM / 128;     // gload per thread per A-half (2 or 1)
  constexpr int LB = 2;            // per B-half
  constexpr int WS = 2 * (LA + LB);  // steady vmcnt (8 or 6)
  constexpr int WT = LA + LB;        // tail vmcnt (4 or 3)
  constexpr int CSH = (CIN == 256) ? 8 : 9;
  static_assert(CIN == (1 << CSH), "CIN pow2");

  __shared__ ushort smA[2][2][BM * 32];
  __shared__ ushort smB[2][2][256 * 32];
  __shared__ int nei_sh[16];

  const int nwg = TO * TN * GSZ;  // 240
  const int cpx = nwg >> 3;
  const int bid = blockIdx.x;
  const int idx = (bid & 7) * cpx + (bid >> 3);
  const int g = idx / (TO * TN);
  const int rem = idx - g * (TO * TN);
  const int nt = rem / TO;
  const int ot = rem - nt * TO;
  const int n0 = nt * BM;
  const int o0 = ot * 256;

  const int t = threadIdx.x;
  if (t < 14) nei_sh[t] = (t < KNB) ? nei[g * KNB + t] : GSZ;
  __syncthreads();

  const int w = t >> 6;  // 0..7
  const int l = t & 63;
  const int lrow = l & 15;
  const int lkg = l >> 4;  // 16B slot within 32-k half
  const int wr = w >> 2;   // 0..1 (M)
  const int wc = w & 3;    // 0..3 (N)

  // staging per-lane offsets (chunk-invariant): row r, slot s = (l&3)^((r>>1)&3)
  int laneA[LA], laneB[LB];
#pragma unroll
  for (int j = 0; j < LA; ++j) {
    const int r = w * (16 * LA) + j * 16 + (l >> 2);
    const int s = (l & 3) ^ ((r >> 1) & 3);
    laneA[j] = ((n0 + r) << CSH) + s * 8;
  }
#pragma unroll
  for (int j = 0; j < LB; ++j) {
    const int r = w * 32 + j * 16 + (l >> 2);
    const int s = (l & 3) ^ ((r >> 1) & 3);
    laneB[j] = (o0 + r) * KTOT + s * 8;
  }

  auto stageA = [&](int buf, int h, int tt) {
    const int k0 = tt * 64;
    const int pbase = nei_sh[k0 >> CSH] * (NPT << CSH) + (k0 & (CIN - 1)) + h * 32;
#pragma unroll
    for (int j = 0; j < LA; ++j)
      gload_lds16(Xin + pbase + laneA[j], &smA[buf][h][(w * (16 * LA) + j * 16) * 32]);
  };
  auto stageB = [&](int buf, int h, int tt) {
    const int kb = tt * 64 + h * 32;
#pragma unroll
    for (int j = 0; j < LB; ++j)
      gload_lds16(Wb + kb + laneB[j], &smB[buf][h][(w * 32 + j * 16) * 32]);
  };

  // swizzled ds_read address (ushort index) for row r, k-slot lkg
  auto ridx = [&](int r) { return r * 32 + ((lkg ^ ((r >> 1) & 3)) << 3); };

  f32x4 acc[M_REP][4] = {};
  s16x8 bfr[4], afr[MH];

  // prologue: tile0 (4 halves) + tile1 k0 halves
  stageA(0, 0, 0); stageB(0, 0, 0);
  stageA(0, 1, 0); stageB(0, 1, 0);
  if (NT > 1) { stageA(1, 0, 1); stageB(1, 0, 1); }
  vwaitN<WS>();  // tile0 k0 halves landed
  __builtin_amdgcn_s_barrier();

#pragma unroll 1
  for (int tt = 0; tt < NT; ++tt) {
    const int buf = tt & 1;
    // ---- phase 0: ks=0, m-lower ----
#pragma unroll
    for (int n = 0; n < 4; ++n) bfr[n] = *(const s16x8*)&smB[buf][0][ridx(wc * 64 + n * 16 + lrow)];
#pragma unroll
    for (int m = 0; m < MH; ++m) afr[m] = *(const s16x8*)&smA[buf][0][ridx(wr * WM + m * 16 + lrow)];
    if (tt + 1 < NT) stageA(buf ^ 1, 1, tt + 1);
    __builtin_amdgcn_s_barrier();
    __builtin_amdgcn_s_setprio(1);
#pragma unroll
    for (int m = 0; m < MH; ++m)
#pragma unroll
      for (int n = 0; n < 4; ++n)
        acc[m][n] = __builtin_amdgcn_mfma_f32_16x16x32_bf16(afr[m], bfr[n], acc[m][n], 0, 0, 0);
    __builtin_amdgcn_s_setprio(0);
    __builtin_amdgcn_s_barrier();
    // ---- phase 1: ks=0, m-upper ----
#pragma unroll
    for (int m = 0; m < MH; ++m) afr[m] = *(const s16x8*)&smA[buf][0][ridx(wr * WM + (MH + m) * 16 + lrow)];
    if (tt + 1 < NT) stageB(buf ^ 1, 1, tt + 1);
    __builtin_amdgcn_s_barrier();
    __builtin_amdgcn_s_setprio(1);
#pragma unroll
    for (int m = 0; m < MH; ++m)
#pragma unroll
      for (int n = 0; n < 4; ++n)
        acc[MH + m][n] = __builtin_amdgcn_mfma_f32_16x16x32_bf16(afr[m], bfr[n], acc[MH + m][n], 0, 0, 0);
    __builtin_amdgcn_s_setprio(0);
    if (tt + 1 < NT) vwaitN<WS>(); else vwaitN<0>();  // k1 halves of tile tt ready
    __builtin_amdgcn_s_barrier();
    // ---- phase 2: ks=1, m-lower ----
#pragma unroll
    for (int n = 0; n < 4; ++n) bfr[n] = *(const s16x8*)&smB[buf][1][ridx(wc * 64 + n * 16 + lrow)];
#pragma unroll
    for (int m = 0; m < MH; ++m) afr[m] = *(const s16x8*)&smA[buf][1][ridx(wr * WM + m * 16 + lrow)];
    if (tt + 2 < NT) stageA(buf, 0, tt + 2);
    __builtin_amdgcn_s_barrier();
    __builtin_amdgcn_s_setprio(1);
#pragma unroll
    for (int m = 0; m < MH; ++m)
#pragma unroll
      for (int n = 0; n < 4; ++n)
        acc[m][n] = __builtin_amdgcn_mfma_f32_16x16x32_bf16(afr[m], bfr[n], acc[m][n], 0, 0, 0);
    __builtin_amdgcn_s_setprio(0);
    __builtin_amdgcn_s_barrier();
    // ---- phase 3: ks=1, m-upper ----
#pragma unroll
    for (int m = 0; m < MH; ++m) afr[m] = *(const s16x8*)&smA[buf][1][ridx(wr * WM + (MH + m) * 16 + lrow)];
    if (tt + 2 < NT) stageB(buf, 0, tt + 2);
    __builtin_amdgcn_s_barrier();
    __builtin_amdgcn_s_setprio(1);
#pragma unroll
    for (int m = 0; m < MH; ++m)
#pragma unroll
      for (int n = 0; n < 4; ++n)
        acc[MH + m][n] = __builtin_amdgcn_mfma_f32_16x16x32_bf16(afr[m], bfr[n], acc[MH + m][n], 0, 0, 0);
    __builtin_amdgcn_s_setprio(0);
    if (tt + 2 < NT) vwaitN<WS>();          // next tile k0 halves ready
    else if (tt + 1 < NT) vwaitN<WT>();
    else vwaitN<0>();
    __builtin_amdgcn_s_barrier();
  }

#pragma unroll
  for (int m = 0; m < M_REP; ++m) {
#pragma unroll
    for (int n = 0; n < 4; ++n) {
      const int oc = o0 + wc * 64 + n * 16 + lrow;
      const float bv = bias[oc];
#pragma unroll
      for (int r = 0; r < 4; ++r) {
        const int row = n0 + wr * WM + m * 16 + lkg * 4 + r;
        float v = acc[m][n][r] + bv;
        if (MODE == 0) {
          if (RELU) v = v > 0.f ? v : 0.f;
          Xout[((size_t)g * NPT + row) * OPAD + oc] = f2bf(v);
        } else {  // MODE 1: residual accumulate
          const size_t ix = ((size_t)g * NPT + row) * OPAD + oc;
          Xout[ix] = f2bf(bf2f(Xout[ix]) + v);
        }
      }
    }
  }
}

// Eq4: 4 split-K partials [4][G][N][64] fp32 -> out: inv [N][32], eqv [N][32][G]
__global__ __launch_bounds__(256) void finalize_k(const float* __restrict__ Eq,
                                                  float* __restrict__ out) {
  const int n = blockIdx.x;
  const int t = threadIdx.x;
  const int c = t & 31;
  const int gs = t >> 5;
  constexpr size_t PART = (size_t)GSZ * NPT * 64;

  float invp = 0.f;
  for (int g = gs; g < GSZ; g += 8) {
    const size_t base = ((size_t)g * NPT + n) * 64 + c;
    float x = Eq[base] + Eq[PART + base] + Eq[2 * PART + base] + Eq[3 * PART + base];
    invp += x;
    float ss = x * x;
#pragma unroll
    for (int m = 16; m >= 1; m >>= 1) ss += __shfl_xor(ss, m, 64);
    float nrm = sqrtf(ss);
    nrm = nrm > 1e-4f ? nrm : 1e-4f;
    out[16384 + ((size_t)n * 32 + c) * GSZ + g] = x / nrm;
  }

  __shared__ float tmp[8][32];
  tmp[gs][c] = invp;
  __syncthreads();
  if (t < 32) {
    float s = 0.f;
#pragma unroll
    for (int i = 0; i < 8; ++i) s += tmp[i][t];
    s *= (1.f / 60.f);
    float ss = s * s;
#pragma unroll
    for (int m = 16; m >= 1; m >>= 1) ss += __shfl_xor(ss, m, 64);
    float nrm = sqrtf(ss);
    nrm = nrm > 1e-4f ? nrm : 1e-4f;
    out[(size_t)n * 32 + t] = s / nrm;
  }
}

extern "C" void kernel_launch(void* const* d_in, const int* in_sizes, int n_in,
                              void* d_out, int out_size, void* d_ws, size_t ws_size,
                              hipStream_t stream) {
  const float* feats = (const float*)d_in[0];
  const int* nei = (const int*)d_in[1];
  const float* W_in = (const float*)d_in[2];
  const float* b_in = (const float*)d_in[3];
  const float* W_r1 = (const float*)d_in[4];
  const float* b_r1 = (const float*)d_in[5];
  const float* W_r2 = (const float*)d_in[6];
  const float* b_r2 = (const float*)d_in[7];
  const float* W_out = (const float*)d_in[8];
  const float* b_out = (const float*)d_in[9];
  float* out = (float*)d_out;

  char* ws = (char*)d_ws;
  size_t off = 0;
  auto alloc = [&](size_t bytes) {
    void* p = ws + off;
    off += (bytes + 255) & ~(size_t)255;
    return p;
  };
  ushort* X0 = (ushort*)alloc((size_t)61 * NPT * 32 * 2);    // 2.0 MB
  ushort* H1 = (ushort*)alloc((size_t)GSZ * NPT * 256 * 2);  // 15.7 MB (h1, then h2)
  ushort* R = (ushort*)alloc((size_t)GSZ * NPT * 512 * 2);   // 31.5 MB; later aliased as Eq4
  ushort* Wb_in = (ushort*)alloc((size_t)256 * 448 * 2);
  ushort* Wb_r1 = (ushort*)alloc((size_t)512 * 3328 * 2);
  ushort* Wb_r2 = (ushort*)alloc((size_t)256 * 6656 * 2);
  ushort* Wb_out = (ushort*)alloc((size_t)64 * 3328 * 2);
  float* Eq4 = (float*)R;  // L4 split-K partials [4][G][N][64] fp32 (R dead after L3)

  prep_feats_k<<<(61 * NPT * 32 + 255) / 256, 256, 0, stream>>>(feats, X0);
  prep_wb_k<<<(256 * 448 + 255) / 256, 256, 0, stream>>>(W_in, Wb_in, 256, 256, 32, 448);
  prep_wb_k<<<(512 * 3328 + 255) / 256, 256, 0, stream>>>(W_r1, Wb_r1, 512, 512, 256, 3328);
  prep_wb_k<<<(256 * 6656 + 255) / 256, 256, 0, stream>>>(W_r2, Wb_r2, 256, 256, 512, 6656);
  prep_wb_k<<<(64 * 3328 + 255) / 256, 256, 0, stream>>>(W_out, Wb_out, 32, 64, 256, 3328);

  // L1: 32 -> 256 (KTOT 448, 7 chunks), 4-wave dbuf, grid 480
  comb_gemm<32, 448, 256, 256, 128, 0, false><<<dim3(2 * 4 * GSZ), dim3(256), 0, stream>>>(
      X0, Wb_in, b_in, nei, H1, nullptr, nullptr, 0, 7);
  // L2: 256 -> 512, relu; 8-phase 256x256, grid 2*2*60=240
  comb8p<256, 3328, 512, 256, 0, true><<<dim3(240), dim3(512), 0, stream>>>(
      H1, Wb_r1, b_r1, nei, R);
  // L3: 512 -> 256, h2 = h1 + comb(r); 8-phase 128x256, grid 4*1*60=240
  comb8p<512, 6656, 256, 128, 1, false><<<dim3(240), dim3(512), 0, stream>>>(
      R, Wb_r2, b_r2, nei, H1);
  // L4: 256 -> 32 (pad 64), split-K x4 -> Eq4 partials (R buffer)
  for (int kp = 0; kp < 4; ++kp) {
    comb_gemm<256, 3328, 64, 32, 64, 2, false><<<dim3(1 * 4 * GSZ), dim3(256), 0, stream>>>(
        H1, Wb_out, b_out, nei, nullptr, Eq4 + (size_t)kp * GSZ * NPT * 64,
        kp == 0 ? feats : nullptr, kp * 13, (kp + 1) * 13);
  }
  finalize_k<<<NPT, 256, 0, stream>>>(Eq4, out);
}

// Round 7
// 330.589 us; speedup vs baseline: 1.2823x; 1.1750x over previous
//
#include <hip/hip_runtime.h>
#include <stdint.h>

#define GSZ 60
#define KNB 13
#define NPT 512

typedef __attribute__((ext_vector_type(4))) float f32x4;
typedef __attribute__((ext_vector_type(16))) float f32x16;
typedef __attribute__((ext_vector_type(8))) short s16x8;

__device__ __forceinline__ ushort f2bf(float f) {
  union { float f; unsigned u; } v; v.f = f;
  unsigned r = v.u + 0x7fffu + ((v.u >> 16) & 1u);
  return (ushort)(r >> 16);
}
__device__ __forceinline__ float bf2f(ushort h) {
  union { unsigned u; float f; } v; v.u = ((unsigned)h) << 16;
  return v.f;
}

// async global->LDS, 16B per lane; dst must be wave-uniform (HW adds lane*16)
__device__ __forceinline__ void gload_lds16(const void* gsrc, void* ldst) {
  __builtin_amdgcn_global_load_lds(
      (const __attribute__((address_space(1))) uint32_t*)gsrc,
      (__attribute__((address_space(3))) uint32_t*)ldst, 16, 0, 0);
}

// feats [N][32][G] fp32 -> X0 [61][N][32] bf16 (panel 60 = zeros, L1 K-padding)
__global__ __launch_bounds__(256) void prep_feats_k(const float* __restrict__ feats,
                                                    ushort* __restrict__ X0) {
  int idx = blockIdx.x * 256 + threadIdx.x;
  if (idx >= 61 * NPT * 32) return;
  int c = idx & 31;
  int t = idx >> 5;
  int n = t % NPT;
  int g = t / NPT;
  X0[idx] = (g < GSZ) ? f2bf(feats[(n * 32 + c) * GSZ + g]) : (ushort)0;
}

// W [O][C][13] fp32 -> Wb [OPAD][KPAD] bf16, Wb[o][k*C+c] = W[o][c][k], zero-padded
__global__ __launch_bounds__(256) void prep_wb_k(const float* __restrict__ W,
                                                 ushort* __restrict__ Wb,
                                                 int O, int OPAD, int C, int KPAD) {
  int idx = blockIdx.x * 256 + threadIdx.x;
  if (idx >= OPAD * KPAD) return;
  int o = idx / KPAD;
  int kk = idx - o * KPAD;
  int k = kk / C;
  int c = kk - k * C;
  Wb[idx] = (o < O && k < KNB) ? f2bf(W[(o * C + c) * KNB + k]) : (ushort)0;
}

// ---------------- 4-wave 128xBN dbuf kernel, 16x16x32 MFMA (L1, L4) ----------------
template <int CIN, int KTOT, int OPAD, int OREAL, int BN, int MODE, bool RELU>
__global__ __launch_bounds__(256) void comb_gemm(
    const ushort* __restrict__ Xin, const ushort* __restrict__ Wb,
    const float* __restrict__ bias, const int* __restrict__ nei,
    ushort* __restrict__ Xout, float* __restrict__ Eq,
    const float* __restrict__ feats) {
  constexpr int BM = 128;
  constexpr int BK = 64;
  constexpr int NCH = KTOT / BK;
  constexpr int TO = OPAD / BN;
  constexpr int TN = NPT / BM;
  constexpr int WN = BN / 2;
  constexpr int N_REP = WN / 16;
  constexpr int M_REP = 4;
  constexpr int CSH = (CIN == 32) ? 5 : (CIN == 256) ? 8 : 9;
  static_assert(CIN == (1 << CSH), "CIN pow2");

  __shared__ ushort smA[2][BM * BK];
  __shared__ ushort smB[2][BN * BK];
  __shared__ int nei_sh[16];

  const int nwg = TO * TN * GSZ;
  const int cpx = nwg >> 3;
  const int bid = blockIdx.x;
  const int idx = (bid & 7) * cpx + (bid >> 3);
  const int g = idx / (TO * TN);
  const int rem = idx - g * (TO * TN);
  const int nt = rem / TO;
  const int ot = rem - nt * TO;
  const int n0 = nt * BM;
  const int o0 = ot * BN;

  const int t = threadIdx.x;
  if (t < 14) nei_sh[t] = (t < KNB) ? nei[g * KNB + t] : GSZ;
  __syncthreads();

  const int w = t >> 6;
  const int l = t & 63;
  const int lrow = l & 15;
  const int lkg = l >> 4;
  const int wr = w >> 1;
  const int wc = w & 1;
  const int srow_w = w * 8;
  const int sr = l >> 3;
  const int slot = l & 7;

  int laneA[BM / 32], laneB[BN / 32], swz[BM / 32];
#pragma unroll
  for (int j = 0; j < BM / 32; ++j) {
    const int r = j * 32 + srow_w + sr;
    swz[j] = (slot ^ (r & 7)) << 3;
    laneA[j] = ((n0 + r) << CSH) + swz[j];
  }
#pragma unroll
  for (int j = 0; j < BN / 32; ++j) {
    const int r = j * 32 + srow_w + sr;
    laneB[j] = (o0 + r) * KTOT + ((slot ^ (r & 7)) << 3);
  }

  auto stage = [&](int buf, int q) {
    const int c0 = q * BK;
    if constexpr (CIN >= 64) {
      const int pbase = nei_sh[c0 >> CSH] * (NPT << CSH) + (c0 & (CIN - 1));
#pragma unroll
      for (int j = 0; j < BM / 32; ++j)
        gload_lds16(Xin + pbase + laneA[j], &smA[buf][(j * 32 + srow_w) * BK]);
    } else {
#pragma unroll
      for (int j = 0; j < BM / 32; ++j) {
        const int r = j * 32 + srow_w + sr;
        const int kk = c0 + swz[j];
        const int nbr = kk >> CSH;
        const int cc = kk & (CIN - 1);
        gload_lds16(Xin + ((nei_sh[nbr] * NPT + n0 + r) << CSH) + cc,
                    &smA[buf][(j * 32 + srow_w) * BK]);
      }
    }
#pragma unroll
    for (int j = 0; j < BN / 32; ++j)
      gload_lds16(Wb + laneB[j] + c0, &smB[buf][(j * 32 + srow_w) * BK]);
  };

  f32x4 acc[M_REP][N_REP] = {};

  stage(0, 0);
  asm volatile("s_waitcnt vmcnt(0)" ::: "memory");
  __builtin_amdgcn_s_barrier();

  int cur = 0;
#pragma unroll 1
  for (int q = 0; q < NCH; ++q) {
    if (q + 1 < NCH) stage(cur ^ 1, q + 1);
#pragma unroll
    for (int ks = 0; ks < 2; ++ks) {
      const int cb = ks * 4 + lkg;
      s16x8 bf[N_REP];
#pragma unroll
      for (int n = 0; n < N_REP; ++n) {
        const int r = wc * WN + n * 16 + lrow;
        bf[n] = *(const s16x8*)&smB[cur][r * BK + ((cb ^ (r & 7)) << 3)];
      }
#pragma unroll
      for (int m = 0; m < M_REP; ++m) {
        const int r = wr * 64 + m * 16 + lrow;
        s16x8 af = *(const s16x8*)&smA[cur][r * BK + ((cb ^ (r & 7)) << 3)];
#pragma unroll
        for (int n = 0; n < N_REP; ++n)
          acc[m][n] = __builtin_amdgcn_mfma_f32_16x16x32_bf16(af, bf[n], acc[m][n], 0, 0, 0);
      }
    }
    asm volatile("s_waitcnt vmcnt(0)" ::: "memory");
    __builtin_amdgcn_s_barrier();
    cur ^= 1;
  }

#pragma unroll
  for (int m = 0; m < M_REP; ++m) {
#pragma unroll
    for (int n = 0; n < N_REP; ++n) {
      const int oc = o0 + wc * WN + n * 16 + lrow;
      float bv;
      if (MODE == 2)
        bv = (oc < OREAL) ? bias[oc] : 0.f;
      else
        bv = bias[oc];
#pragma unroll
      for (int r = 0; r < 4; ++r) {
        const int row = n0 + wr * 64 + m * 16 + lkg * 4 + r;
        float v = acc[m][n][r] + bv;
        if (MODE == 0) {
          if (RELU) v = v > 0.f ? v : 0.f;
          Xout[((size_t)g * NPT + row) * OPAD + oc] = f2bf(v);
        } else if (MODE == 1) {
          const size_t ix = ((size_t)g * NPT + row) * OPAD + oc;
          Xout[ix] = f2bf(bf2f(Xout[ix]) + v);
        } else {
          const float add = (oc < OREAL) ? feats[((size_t)row * 32 + oc) * GSZ + g] : 0.f;
          Eq[((size_t)g * NPT + row) * 64 + oc] = v + add;
        }
      }
    }
  }
}

// ---------------- 4-wave 128x128 dbuf kernel, 32x32x16 MFMA (L2, L3) ----------------
// Same staging/swizzle/sync as comb_gemm; only fragment shape differs.
// A/B frag: lane l holds row (l&31), k = 8*(l>>5)+j. C/D: col=l&31,
// row = (reg&3) + 8*(reg>>2) + 4*(l>>5)  [m74/m101-verified mapping].
template <int CIN, int KTOT, int OPAD, int MODE, bool RELU>
__global__ __launch_bounds__(256) void comb_gemm32(
    const ushort* __restrict__ Xin, const ushort* __restrict__ Wb,
    const float* __restrict__ bias, const int* __restrict__ nei,
    ushort* __restrict__ Xout) {
  constexpr int BM = 128, BN = 128, BK = 64;
  constexpr int NCH = KTOT / BK;
  constexpr int TO = OPAD / BN;
  constexpr int TN = NPT / BM;  // 4
  constexpr int CSH = (CIN == 256) ? 8 : 9;
  static_assert(CIN == (1 << CSH), "CIN pow2");

  __shared__ ushort smA[2][BM * BK];
  __shared__ ushort smB[2][BN * BK];
  __shared__ int nei_sh[16];

  const int nwg = TO * TN * GSZ;
  const int cpx = nwg >> 3;
  const int bid = blockIdx.x;
  const int idx = (bid & 7) * cpx + (bid >> 3);
  const int g = idx / (TO * TN);
  const int rem = idx - g * (TO * TN);
  const int nt = rem / TO;
  const int ot = rem - nt * TO;
  const int n0 = nt * BM;
  const int o0 = ot * BN;

  const int t = threadIdx.x;
  if (t < 14) nei_sh[t] = (t < KNB) ? nei[g * KNB + t] : GSZ;
  __syncthreads();

  const int w = t >> 6;
  const int l = t & 63;
  const int l31 = l & 31;
  const int kg = l >> 5;   // k-group 0..1 (8 k each)
  const int wr = w >> 1;
  const int wc = w & 1;
  const int srow_w = w * 8;
  const int sr = l >> 3;
  const int slot = l & 7;

  int laneA[4], laneB[4];
#pragma unroll
  for (int j = 0; j < 4; ++j) {
    const int r = j * 32 + srow_w + sr;
    const int sz = (slot ^ (r & 7)) << 3;
    laneA[j] = ((n0 + r) << CSH) + sz;
    laneB[j] = (o0 + r) * KTOT + sz;
  }

  auto stage = [&](int buf, int q) {
    const int c0 = q * BK;
    const int pbase = nei_sh[c0 >> CSH] * (NPT << CSH) + (c0 & (CIN - 1));
#pragma unroll
    for (int j = 0; j < 4; ++j)
      gload_lds16(Xin + pbase + laneA[j], &smA[buf][(j * 32 + srow_w) * BK]);
#pragma unroll
    for (int j = 0; j < 4; ++j)
      gload_lds16(Wb + laneB[j] + c0, &smB[buf][(j * 32 + srow_w) * BK]);
  };

  f32x16 acc[2][2] = {};

  stage(0, 0);
  asm volatile("s_waitcnt vmcnt(0)" ::: "memory");
  __builtin_amdgcn_s_barrier();

  int cur = 0;
#pragma unroll 1
  for (int q = 0; q < NCH; ++q) {
    if (q + 1 < NCH) stage(cur ^ 1, q + 1);
#pragma unroll
    for (int ks = 0; ks < 4; ++ks) {  // 4 k-steps of 16 within BK=64
      const int cb = ks * 2 + kg;     // 16B slot index 0..7
      s16x8 bf[2], af[2];
#pragma unroll
      for (int n = 0; n < 2; ++n) {
        const int r = wc * 64 + n * 32 + l31;
        bf[n] = *(const s16x8*)&smB[cur][r * BK + ((cb ^ (r & 7)) << 3)];
      }
#pragma unroll
      for (int m = 0; m < 2; ++m) {
        const int r = wr * 64 + m * 32 + l31;
        af[m] = *(const s16x8*)&smA[cur][r * BK + ((cb ^ (r & 7)) << 3)];
      }
#pragma unroll
      for (int m = 0; m < 2; ++m)
#pragma unroll
        for (int n = 0; n < 2; ++n)
          acc[m][n] = __builtin_amdgcn_mfma_f32_32x32x16_bf16(af[m], bf[n], acc[m][n], 0, 0, 0);
    }
    asm volatile("s_waitcnt vmcnt(0)" ::: "memory");
    __builtin_amdgcn_s_barrier();
    cur ^= 1;
  }

#pragma unroll
  for (int m = 0; m < 2; ++m) {
#pragma unroll
    for (int n = 0; n < 2; ++n) {
      const int oc = o0 + wc * 64 + n * 32 + l31;
      const float bv = bias[oc];
#pragma unroll
      for (int reg = 0; reg < 16; ++reg) {
        const int row = n0 + wr * 64 + m * 32 + 4 * kg + (reg & 3) + 8 * (reg >> 2);
        float v = acc[m][n][reg] + bv;
        if (MODE == 0) {
          if (RELU) v = v > 0.f ? v : 0.f;
          Xout[((size_t)g * NPT + row) * OPAD + oc] = f2bf(v);
        } else {  // MODE 1: residual accumulate
          const size_t ix = ((size_t)g * NPT + row) * OPAD + oc;
          Xout[ix] = f2bf(bf2f(Xout[ix]) + v);
        }
      }
    }
  }
}

// Eq [G][N][64] fp32 -> out: inv [N][32] normalized, eqv [N][32][G] normalized
__global__ __launch_bounds__(256) void finalize_k(const float* __restrict__ Eq,
                                                  float* __restrict__ out) {
  const int n = blockIdx.x;
  const int t = threadIdx.x;
  const int c = t & 31;
  const int gs = t >> 5;  // 0..7

  float invp = 0.f;
  for (int g = gs; g < GSZ; g += 8) {
    float x = Eq[((size_t)g * NPT + n) * 64 + c];
    invp += x;
    float ss = x * x;
#pragma unroll
    for (int m = 16; m >= 1; m >>= 1) ss += __shfl_xor(ss, m, 64);
    float nrm = sqrtf(ss);
    nrm = nrm > 1e-4f ? nrm : 1e-4f;
    out[16384 + ((size_t)n * 32 + c) * GSZ + g] = x / nrm;
  }

  __shared__ float tmp[8][32];
  tmp[gs][c] = invp;
  __syncthreads();
  if (t < 32) {
    float s = 0.f;
#pragma unroll
    for (int i = 0; i < 8; ++i) s += tmp[i][t];
    s *= (1.f / 60.f);
    float ss = s * s;
#pragma unroll
    for (int m = 16; m >= 1; m >>= 1) ss += __shfl_xor(ss, m, 64);
    float nrm = sqrtf(ss);
    nrm = nrm > 1e-4f ? nrm : 1e-4f;
    out[(size_t)n * 32 + t] = s / nrm;
  }
}

extern "C" void kernel_launch(void* const* d_in, const int* in_sizes, int n_in,
                              void* d_out, int out_size, void* d_ws, size_t ws_size,
                              hipStream_t stream) {
  const float* feats = (const float*)d_in[0];
  const int* nei = (const int*)d_in[1];
  const float* W_in = (const float*)d_in[2];
  const float* b_in = (const float*)d_in[3];
  const float* W_r1 = (const float*)d_in[4];
  const float* b_r1 = (const float*)d_in[5];
  const float* W_r2 = (const float*)d_in[6];
  const float* b_r2 = (const float*)d_in[7];
  const float* W_out = (const float*)d_in[8];
  const float* b_out = (const float*)d_in[9];
  float* out = (float*)d_out;

  char* ws = (char*)d_ws;
  size_t off = 0;
  auto alloc = [&](size_t bytes) {
    void* p = ws + off;
    off += (bytes + 255) & ~(size_t)255;
    return p;
  };
  ushort* X0 = (ushort*)alloc((size_t)61 * NPT * 32 * 2);      // 2.0 MB (panel 60 = zeros)
  ushort* H1 = (ushort*)alloc((size_t)GSZ * NPT * 256 * 2);    // 15.7 MB (h1, then h2 in-place)
  ushort* R = (ushort*)alloc((size_t)GSZ * NPT * 512 * 2);     // 31.5 MB
  float* Eq = (float*)alloc((size_t)GSZ * NPT * 64 * 4);       // 7.9 MB
  ushort* Wb_in = (ushort*)alloc((size_t)256 * 448 * 2);
  ushort* Wb_r1 = (ushort*)alloc((size_t)512 * 3328 * 2);
  ushort* Wb_r2 = (ushort*)alloc((size_t)256 * 6656 * 2);
  ushort* Wb_out = (ushort*)alloc((size_t)64 * 3328 * 2);

  prep_feats_k<<<(61 * NPT * 32 + 255) / 256, 256, 0, stream>>>(feats, X0);
  prep_wb_k<<<(256 * 448 + 255) / 256, 256, 0, stream>>>(W_in, Wb_in, 256, 256, 32, 448);
  prep_wb_k<<<(512 * 3328 + 255) / 256, 256, 0, stream>>>(W_r1, Wb_r1, 512, 512, 256, 3328);
  prep_wb_k<<<(256 * 6656 + 255) / 256, 256, 0, stream>>>(W_r2, Wb_r2, 256, 256, 512, 6656);
  prep_wb_k<<<(64 * 3328 + 255) / 256, 256, 0, stream>>>(W_out, Wb_out, 32, 64, 256, 3328);

  dim3 blk(256);
  // L1: 32 -> 256 (KTOT 416 padded to 448), 16x16 kernel
  comb_gemm<32, 448, 256, 256, 128, 0, false><<<dim3(2 * 4 * GSZ), blk, 0, stream>>>(
      X0, Wb_in, b_in, nei, H1, nullptr, nullptr);
  // L2: 256 -> 512, relu; 32x32 kernel, grid 960
  comb_gemm32<256, 3328, 512, 0, true><<<dim3(4 * 4 * GSZ), blk, 0, stream>>>(
      H1, Wb_r1, b_r1, nei, R);
  // L3: 512 -> 256, h2 = h1 + comb(r); 32x32 kernel, grid 480
  comb_gemm32<512, 6656, 256, 1, false><<<dim3(2 * 4 * GSZ), blk, 0, stream>>>(
      R, Wb_r2, b_r2, nei, H1);
  // L4: 256 -> 32 (pad 64), + feats -> Eq fp32; 16x16 kernel
  comb_gemm<256, 3328, 64, 32, 64, 2, false><<<dim3(1 * 4 * GSZ), blk, 0, stream>>>(
      H1, Wb_out, b_out, nei, nullptr, Eq, feats);
  finalize_k<<<NPT, 256, 0, stream>>>(Eq, out);
}